// Round 2
// baseline (349.358 us; speedup 1.0000x reference)
//
#include <hip/hip_runtime.h>
#include <math.h>

// x: [B,1,W,F] fp32, weights0: [F] fp32
// out: [B,1,2W-1,F] fp32; even rows = x[i], odd rows = s*x[i] + (1-s)*x[i+1],
// s = sigmoid(weights0).
//
// Pair-thread structure: one thread owns one float4 column of input row p and
// emits BOTH output rows 2p (copy) and 2p+1 (blend with row p+1). This
//   - halves the thread count vs the row-per-wave version,
//   - cuts cache-level reads of x from 3x to 2x (each x row is read as 'a' by
//     pair p and as 'c' by pair p-1),
//   - makes the batch/row decomposition pure shifts (W = 2^13; no magic-mul
//     division by OW=16383 anywhere),
//   - keeps every wave's loads/stores fully coalesced 1 KB segments:
//     a @ p*64+lane, c @ (p+1)*64+lane, stores @ p*128+lane and p*128+64+lane.
//
// Sigmoid via v_exp_f32 + v_rcp_f32 (~1e-6 abs error on a (0,1) value; the
// harness absmax band is 0.0156). Output is write-once -> nontemporal stores
// (native ext_vector_type(4) — HIP's float4 wrapper is rejected by the
// builtin) so the stream does not evict x from L2/L3.
constexpr int B  = 16;
constexpr int W  = 8192;           // 2^13
constexpr int F  = 256;
constexpr int F4 = F / 4;          // 64 float4 per row == one wave
constexpr int OW = 2 * W - 1;      // 16383 output rows per batch

constexpr int THREADS = B * W * F4;       // 8,388,608: one thread per input float4
constexpr int BLOCK   = 256;
constexpr int GRID    = THREADS / BLOCK;  // 32,768 (divides exactly)

typedef float f32x4 __attribute__((ext_vector_type(4)));

__device__ __forceinline__ float fast_sigmoid(float w) {
    // sigmoid(w) = 1/(1+exp(-w)) = rcp(1 + 2^(-w*log2(e)))
    const float e = __builtin_amdgcn_exp2f(w * -1.4426950408889634f);
    return __builtin_amdgcn_rcpf(1.0f + e);
}

__global__ __launch_bounds__(BLOCK) void upsampler_kernel(
    const f32x4* __restrict__ x4,
    const float* __restrict__ w0,
    f32x4* __restrict__ out4)
{
    const unsigned tid  = blockIdx.x * BLOCK + threadIdx.x;
    const unsigned lane = tid & 63u;              // float4 column within the row
    const unsigned rw   = tid >> 6;               // global input row, 0 .. B*W-1
    const unsigned b    = rw >> 13;               // batch (W = 2^13)
    const unsigned p    = rw & (unsigned)(W - 1); // input row within batch

    const f32x4* xb = x4   + (size_t)b * W  * F4;
    f32x4*       ob = out4 + (size_t)b * OW * F4;

    const f32x4 a = xb[(size_t)p * F4 + lane];

    if (p < (unsigned)(W - 1)) {
        // interior pair: emit rows 2p (copy) and 2p+1 (blend)
        const f32x4 c  = xb[(size_t)(p + 1) * F4 + lane];
        const f32x4 wv = ((const f32x4*)w0)[lane];

        f32x4 s;
        s[0] = fast_sigmoid(wv[0]);
        s[1] = fast_sigmoid(wv[1]);
        s[2] = fast_sigmoid(wv[2]);
        s[3] = fast_sigmoid(wv[3]);

        const f32x4 v = s * a + (1.0f - s) * c;

        __builtin_nontemporal_store(a, &ob[(size_t)p * (2 * F4) + lane]);
        __builtin_nontemporal_store(v, &ob[(size_t)p * (2 * F4) + F4 + lane]);
    } else {
        // p == W-1: final even row 2(W-1) = OW-1 only (no odd partner)
        __builtin_nontemporal_store(a, &ob[(size_t)p * (2 * F4) + lane]);
    }
}

extern "C" void kernel_launch(void* const* d_in, const int* in_sizes, int n_in,
                              void* d_out, int out_size, void* d_ws, size_t ws_size,
                              hipStream_t stream) {
    const float* x  = (const float*)d_in[0];   // [B,1,W,F] fp32
    const float* w0 = (const float*)d_in[1];   // [F] fp32
    float* out = (float*)d_out;                // [B,1,2W-1,F] fp32

    upsampler_kernel<<<GRID, BLOCK, 0, stream>>>(
        (const f32x4*)x, w0, (f32x4*)out);
}

// Round 3
// 341.529 us; speedup vs baseline: 1.0229x; 1.0229x over previous
//
#include <hip/hip_runtime.h>
#include <math.h>

// x: [B,1,W,F] fp32, weights0: [F] fp32
// out: [B,1,2W-1,F] fp32; even rows = x[i], odd rows = s*x[i] + (1-s)*x[i+1],
// s = sigmoid(weights0).
//
// Copy-ubench structure (m13: float4 copy = 6.29 TB/s): 2048 blocks x 256
// threads, 100% occupancy, each thread owns a FIXED (input row p, float4
// column lane) and loops over the B=16 batches with constant address strides.
//   - sigmoid(w0[lane]) computed ONCE per thread (lane is loop-invariant)
//   - the p==W-1 tail test is wave-uniform and loop-invariant
//   - full unroll over B gives 16 independent {a,c} load pairs for the
//     compiler to software-pipeline -> deep MLP like the copy ubench
//   - all loads/stores remain perfectly coalesced 1 KB wave segments:
//     a @ p*64+lane, c @ (p+1)*64+lane, stores @ p*128+{lane, 64+lane}
// Traffic is the mandatory minimum: 134 MB read (each x row fetched once from
// HBM; the a/c overlap hits L2) + 268 MB written = 402 MB -> 64 us floor.
// Nontemporal stores keep the write-once output stream from evicting x.
constexpr int B  = 16;
constexpr int W  = 8192;           // 2^13
constexpr int F  = 256;
constexpr int F4 = F / 4;          // 64 float4 per row == one wave
constexpr int OW = 2 * W - 1;      // 16383 output rows per batch

constexpr int BLOCK = 256;
constexpr int GRID  = (W * F4) / BLOCK;   // 2048 blocks: one thread per (p,lane)

typedef float f32x4 __attribute__((ext_vector_type(4)));

__device__ __forceinline__ float fast_sigmoid(float w) {
    // sigmoid(w) = 1/(1+exp(-w)) = rcp(1 + 2^(-w*log2(e)))
    const float e = __builtin_amdgcn_exp2f(w * -1.4426950408889634f);
    return __builtin_amdgcn_rcpf(1.0f + e);
}

__global__ __launch_bounds__(BLOCK) void upsampler_kernel(
    const f32x4* __restrict__ x4,
    const float* __restrict__ w0,
    f32x4* __restrict__ out4)
{
    const unsigned tid  = blockIdx.x * BLOCK + threadIdx.x;  // 0 .. W*F4-1
    const unsigned lane = tid & 63u;      // float4 column within the row
    const unsigned p    = tid >> 6;       // input row within batch, 0..W-1

    // Per-thread invariants: blend weights + interior flag.
    const f32x4 wv = ((const f32x4*)w0)[lane];
    f32x4 s;
    s[0] = fast_sigmoid(wv[0]);
    s[1] = fast_sigmoid(wv[1]);
    s[2] = fast_sigmoid(wv[2]);
    s[3] = fast_sigmoid(wv[3]);
    const f32x4 t = 1.0f - s;
    const bool interior = (p < (unsigned)(W - 1));  // wave-uniform

    const f32x4* xp = x4   + (size_t)p *      F4  + lane;  // &x[0][p][lane]
    f32x4*       op = out4 + (size_t)p * (2 * F4) + lane;  // &out[0][2p][lane]

    #pragma unroll
    for (int b = 0; b < B; ++b) {
        const f32x4 a = xp[0];
        __builtin_nontemporal_store(a, op);          // even row 2p = x[p]
        if (interior) {
            const f32x4 c = xp[F4];                  // x[p+1]
            const f32x4 v = s * a + t * c;
            __builtin_nontemporal_store(v, op + F4); // odd row 2p+1
        }
        xp += (size_t)W  * F4;   // next batch of x
        op += (size_t)OW * F4;   // next batch of out
    }
}

extern "C" void kernel_launch(void* const* d_in, const int* in_sizes, int n_in,
                              void* d_out, int out_size, void* d_ws, size_t ws_size,
                              hipStream_t stream) {
    const float* x  = (const float*)d_in[0];   // [B,1,W,F] fp32
    const float* w0 = (const float*)d_in[1];   // [F] fp32
    float* out = (float*)d_out;                // [B,1,2W-1,F] fp32

    upsampler_kernel<<<GRID, BLOCK, 0, stream>>>(
        (const f32x4*)x, w0, (f32x4*)out);
}